// Round 1
// baseline (981.023 us; speedup 1.0000x reference)
//
#include <hip/hip_runtime.h>

#define N_NODES 100000
#define N_EDGES 3200000
#define F_IN    512
#define HID     16
#define NCLS    10

// ---------------------------------------------------------------- degrees
__global__ __launch_bounds__(256) void k_deg_init(float* __restrict__ deg) {
    int i = blockIdx.x * 256 + threadIdx.x;
    if (i < N_NODES) deg[i] = 1.0f;  // self-loop contributes 1
}

__global__ __launch_bounds__(256) void k_deg_count(const int* __restrict__ dst,
                                                   float* __restrict__ deg) {
    int e = blockIdx.x * 256 + threadIdx.x;
    if (e < N_EDGES) atomicAdd(deg + dst[e], 1.0f);
}

__global__ __launch_bounds__(256) void k_rsqrt(float* __restrict__ deg) {
    int i = blockIdx.x * 256 + threadIdx.x;
    if (i < N_NODES) deg[i] = rsqrtf(deg[i]);  // deg >= 1 (self-loop), no zero guard needed
}

// ------------------------------------------------- h1 = x @ W1  (wave per node)
// W1 (512x16 = 32KB) lives in VGPRs: lane owns k = lane*8..lane*8+7 rows.
__global__ __launch_bounds__(256) void k_gemm1(const float* __restrict__ x,
                                               const float* __restrict__ W1,
                                               float* __restrict__ h1) {
    const int lane = threadIdx.x & 63;
    const int wid = (blockIdx.x * 256 + threadIdx.x) >> 6;
    const int nwaves = (gridDim.x * 256) >> 6;

    float w[8][16];
#pragma unroll
    for (int i = 0; i < 8; ++i) {
        const float* wr = W1 + (lane * 8 + i) * 16;
#pragma unroll
        for (int j = 0; j < 16; ++j) w[i][j] = wr[j];
    }

    for (int n = wid; n < N_NODES; n += nwaves) {
        const float4* xr = (const float4*)(x + (size_t)n * F_IN);
        float4 a = xr[lane * 2];
        float4 b = xr[lane * 2 + 1];
        float xv[8] = {a.x, a.y, a.z, a.w, b.x, b.y, b.z, b.w};
        float acc[16];
#pragma unroll
        for (int j = 0; j < 16; ++j) acc[j] = 0.f;
#pragma unroll
        for (int i = 0; i < 8; ++i)
#pragma unroll
            for (int j = 0; j < 16; ++j) acc[j] = fmaf(xv[i], w[i][j], acc[j]);
        // butterfly reduce across the 64 lanes
#pragma unroll
        for (int off = 32; off > 0; off >>= 1)
#pragma unroll
            for (int j = 0; j < 16; ++j) acc[j] += __shfl_xor(acc[j], off, 64);
        if (lane == 0) {
            float4* o = (float4*)(h1 + n * HID);
            o[0] = make_float4(acc[0], acc[1], acc[2], acc[3]);
            o[1] = make_float4(acc[4], acc[5], acc[6], acc[7]);
            o[2] = make_float4(acc[8], acc[9], acc[10], acc[11]);
            o[3] = make_float4(acc[12], acc[13], acc[14], acc[15]);
        }
    }
}

// --------------------------------- agg1 init: self-loop term + bias
__global__ __launch_bounds__(256) void k_init_agg1(const float* __restrict__ h1,
                                                   const float* __restrict__ dinv,
                                                   const float* __restrict__ b1,
                                                   float* __restrict__ agg1) {
    int t = blockIdx.x * 256 + threadIdx.x;
    if (t < N_NODES * HID) {
        int n = t >> 4, j = t & 15;
        float di = dinv[n];
        agg1[t] = h1[t] * di * di + b1[j];
    }
}

// --------------------------------- layer-1 scatter: 16 threads per edge
__global__ __launch_bounds__(256) void k_edge1(const int* __restrict__ ei,
                                               const float* __restrict__ dinv,
                                               const float* __restrict__ h1,
                                               float* __restrict__ agg1) {
    int t = blockIdx.x * 256 + threadIdx.x;
    int e = t >> 4, j = t & 15;
    if (e >= N_EDGES) return;
    int s = ei[e], d = ei[N_EDGES + e];
    float w = dinv[s] * dinv[d];
    atomicAdd(agg1 + d * HID + j, h1[s * HID + j] * w);
}

// --------------------------------- relu + p = h2 @ W2, and init out with self-loop+bias
__global__ __launch_bounds__(256) void k_gemm2(const float* __restrict__ agg1,
                                               const float* __restrict__ W2,
                                               const float* __restrict__ b2,
                                               const float* __restrict__ dinv,
                                               float* __restrict__ p,
                                               float* __restrict__ out) {
    int t = blockIdx.x * 256 + threadIdx.x;
    if (t >= N_NODES * NCLS) return;
    int n = t / NCLS, c = t - n * NCLS;
    const float* row = agg1 + n * HID;
    float v = 0.f;
#pragma unroll
    for (int j = 0; j < HID; ++j)
        v = fmaf(fmaxf(row[j], 0.f), W2[j * NCLS + c], v);
    p[t] = v;
    float di = dinv[n];
    out[t] = v * di * di + b2[c];
}

// --------------------------------- layer-2 scatter: 10 threads per edge
__global__ __launch_bounds__(256) void k_edge2(const int* __restrict__ ei,
                                               const float* __restrict__ dinv,
                                               const float* __restrict__ p,
                                               float* __restrict__ out) {
    int t = blockIdx.x * 256 + threadIdx.x;
    if (t >= N_EDGES * NCLS) return;
    int e = t / NCLS, c = t - e * NCLS;
    int s = ei[e], d = ei[N_EDGES + e];
    float w = dinv[s] * dinv[d];
    atomicAdd(out + d * NCLS + c, p[s * NCLS + c] * w);
}

// --------------------------------- log_softmax over 10 classes, in place
__global__ __launch_bounds__(256) void k_lsm(float* __restrict__ out) {
    int n = blockIdx.x * 256 + threadIdx.x;
    if (n >= N_NODES) return;
    float v[NCLS];
    float m = -1e30f;
#pragma unroll
    for (int c = 0; c < NCLS; ++c) {
        v[c] = out[n * NCLS + c];
        m = fmaxf(m, v[c]);
    }
    float s = 0.f;
#pragma unroll
    for (int c = 0; c < NCLS; ++c) s += __expf(v[c] - m);
    float l = __logf(s) + m;
#pragma unroll
    for (int c = 0; c < NCLS; ++c) out[n * NCLS + c] = v[c] - l;
}

extern "C" void kernel_launch(void* const* d_in, const int* in_sizes, int n_in,
                              void* d_out, int out_size, void* d_ws, size_t ws_size,
                              hipStream_t stream) {
    const float* x  = (const float*)d_in[0];
    const int*   ei = (const int*)d_in[1];   // [2, E] int32, row0 = src, row1 = dst
    const float* W1 = (const float*)d_in[2];
    const float* b1 = (const float*)d_in[3];
    const float* W2 = (const float*)d_in[4];
    const float* b2 = (const float*)d_in[5];
    float* out = (float*)d_out;

    // workspace layout (floats): dinv[131072 pad] | h1[1.6M pad] | agg1[1.6M pad] | p[1M]
    // total ~4.41M floats = ~17.7 MB
    float* f    = (float*)d_ws;
    float* dinv = f;
    float* h1   = f + 131072;
    float* agg1 = h1 + 1638400;
    float* p    = agg1 + 1638400;

    k_deg_init<<<(N_NODES + 255) / 256, 256, 0, stream>>>(dinv);
    k_deg_count<<<(N_EDGES + 255) / 256, 256, 0, stream>>>(ei + N_EDGES, dinv);
    k_rsqrt<<<(N_NODES + 255) / 256, 256, 0, stream>>>(dinv);
    k_gemm1<<<2048, 256, 0, stream>>>(x, W1, h1);
    k_init_agg1<<<(N_NODES * HID + 255) / 256, 256, 0, stream>>>(h1, dinv, b1, agg1);
    k_edge1<<<(N_EDGES * HID + 255) / 256, 256, 0, stream>>>(ei, dinv, h1, agg1);
    k_gemm2<<<(N_NODES * NCLS + 255) / 256, 256, 0, stream>>>(agg1, W2, b2, dinv, p, out);
    k_edge2<<<(N_EDGES * NCLS + 255) / 256, 256, 0, stream>>>(ei, dinv, p, out);
    k_lsm<<<(N_NODES + 255) / 256, 256, 0, stream>>>(out);
}

// Round 2
// 936.812 us; speedup vs baseline: 1.0472x; 1.0472x over previous
//
#include <hip/hip_runtime.h>

#define N_NODES 100000
#define N_EDGES 3200000
#define F_IN    512
#define HID     16
#define NCLS    10
#define SCAN_BLOCKS ((N_NODES + 255) / 256)   // 391

// ------------------------------------------------------------- CSR build
__global__ __launch_bounds__(256) void k_zero(int* __restrict__ cnt) {
    int i = blockIdx.x * 256 + threadIdx.x;
    if (i < N_NODES) cnt[i] = 0;
}

__global__ __launch_bounds__(256) void k_hist(const int* __restrict__ dst,
                                              int* __restrict__ cnt) {
    int e = blockIdx.x * 256 + threadIdx.x;
    if (e < N_EDGES) atomicAdd(cnt + dst[e], 1);
}

// block-local exclusive scan of cnt -> row; block totals -> partials; also dinv
__global__ __launch_bounds__(256) void k_scan1(const int* __restrict__ cnt,
                                               int* __restrict__ row,
                                               int* __restrict__ partials,
                                               float* __restrict__ dinv) {
    __shared__ int sh[256];
    int t = threadIdx.x, i = blockIdx.x * 256 + t;
    int v = (i < N_NODES) ? cnt[i] : 0;
    if (i < N_NODES) dinv[i] = rsqrtf((float)(v + 1));  // +1 self-loop
    sh[t] = v;
    __syncthreads();
    for (int off = 1; off < 256; off <<= 1) {
        int add = (t >= off) ? sh[t - off] : 0;
        __syncthreads();
        sh[t] += add;
        __syncthreads();
    }
    if (i < N_NODES) row[i] = sh[t] - v;          // local exclusive
    if (t == 255) partials[blockIdx.x] = sh[255]; // block total
}

__global__ __launch_bounds__(512) void k_scan2(int* __restrict__ partials) {
    __shared__ int sh[512];
    int t = threadIdx.x;
    int v = (t < SCAN_BLOCKS) ? partials[t] : 0;
    sh[t] = v;
    __syncthreads();
    for (int off = 1; off < 512; off <<= 1) {
        int add = (t >= off) ? sh[t - off] : 0;
        __syncthreads();
        sh[t] += add;
        __syncthreads();
    }
    if (t < SCAN_BLOCKS) partials[t] = sh[t] - v;  // exclusive
}

// finalize row (+block offset), init cursors head=row, set row[N]=E
// NOTE: head aliases cnt's buffer — each thread reads cnt[i] before writing head[i].
__global__ __launch_bounds__(256) void k_scan3(const int* cnt, int* row,
                                               const int* partials, int* head) {
    int i = blockIdx.x * 256 + threadIdx.x;
    if (i >= N_NODES) return;
    int c = cnt[i];
    int r = row[i] + partials[blockIdx.x];
    row[i] = r;
    head[i] = r;
    if (i == N_NODES - 1) row[N_NODES] = r + c;
}

__global__ __launch_bounds__(256) void k_place(const int* __restrict__ ei,
                                               int* __restrict__ head,
                                               int* __restrict__ srcs) {
    int e = blockIdx.x * 256 + threadIdx.x;
    if (e >= N_EDGES) return;
    int s = ei[e], d = ei[N_EDGES + e];
    int pos = atomicAdd(head + d, 1);
    srcs[pos] = s;
}

// ------------------------------------------------- h1 = x @ W1  (wave per node)
__global__ __launch_bounds__(256) void k_gemm1(const float* __restrict__ x,
                                               const float* __restrict__ W1,
                                               float* __restrict__ h1) {
    const int lane = threadIdx.x & 63;
    const int wid = (blockIdx.x * 256 + threadIdx.x) >> 6;
    const int nwaves = (gridDim.x * 256) >> 6;

    float w[8][16];
#pragma unroll
    for (int i = 0; i < 8; ++i) {
        const float* wr = W1 + (lane * 8 + i) * 16;
#pragma unroll
        for (int j = 0; j < 16; ++j) w[i][j] = wr[j];
    }

    for (int n = wid; n < N_NODES; n += nwaves) {
        const float4* xr = (const float4*)(x + (size_t)n * F_IN);
        float4 a = xr[lane * 2];
        float4 b = xr[lane * 2 + 1];
        float xv[8] = {a.x, a.y, a.z, a.w, b.x, b.y, b.z, b.w};
        float acc[16];
#pragma unroll
        for (int j = 0; j < 16; ++j) acc[j] = 0.f;
#pragma unroll
        for (int i = 0; i < 8; ++i)
#pragma unroll
            for (int j = 0; j < 16; ++j) acc[j] = fmaf(xv[i], w[i][j], acc[j]);
#pragma unroll
        for (int off = 32; off > 0; off >>= 1)
#pragma unroll
            for (int j = 0; j < 16; ++j) acc[j] += __shfl_xor(acc[j], off, 64);
        if (lane == 0) {
            float4* o = (float4*)(h1 + n * HID);
            o[0] = make_float4(acc[0], acc[1], acc[2], acc[3]);
            o[1] = make_float4(acc[4], acc[5], acc[6], acc[7]);
            o[2] = make_float4(acc[8], acc[9], acc[10], acc[11]);
            o[3] = make_float4(acc[12], acc[13], acc[14], acc[15]);
        }
    }
}

// ------------------- layer-1 aggregate (gather), fused +b1 and relu
__global__ __launch_bounds__(256) void k_edge1g(const int* __restrict__ row,
                                                const int* __restrict__ srcs,
                                                const float* __restrict__ dinv,
                                                const float* __restrict__ h1,
                                                const float* __restrict__ b1,
                                                float* __restrict__ agg1) {
    int t = blockIdx.x * 256 + threadIdx.x;
    if (t >= N_NODES * HID) return;
    int n = t >> 4, j = t & 15;
    float dn = dinv[n];
    float sum = h1[t] * dn;  // self-loop: dn*dn*h1 = dn*(dn*h1)
    int k1 = row[n + 1];
    for (int k = row[n]; k < k1; ++k) {
        int s = srcs[k];                       // wave-broadcast load
        sum = fmaf(dinv[s], h1[s * HID + j], sum);  // coalesced 64B per 16 lanes
    }
    agg1[t] = fmaxf(fmaf(dn, sum, b1[j]), 0.f);
}

// ------------------- p = relu(agg1) @ W2   (relu already applied in agg1)
__global__ __launch_bounds__(256) void k_gemm2(const float* __restrict__ agg1,
                                               const float* __restrict__ W2,
                                               float* __restrict__ p) {
    int t = blockIdx.x * 256 + threadIdx.x;
    if (t >= N_NODES * NCLS) return;
    int n = t / NCLS, c = t - n * NCLS;
    const float* r = agg1 + n * HID;
    float v = 0.f;
#pragma unroll
    for (int j = 0; j < HID; ++j) v = fmaf(r[j], W2[j * NCLS + c], v);
    p[t] = v;
}

// ------------------- layer-2 aggregate (gather), fused +b2
__global__ __launch_bounds__(256) void k_edge2g(const int* __restrict__ row,
                                                const int* __restrict__ srcs,
                                                const float* __restrict__ dinv,
                                                const float* __restrict__ p,
                                                const float* __restrict__ b2,
                                                float* __restrict__ out) {
    int t = blockIdx.x * 256 + threadIdx.x;
    if (t >= N_NODES * NCLS) return;
    int n = t / NCLS, c = t - n * NCLS;
    float dn = dinv[n];
    float sum = p[t] * dn;  // self-loop
    int k1 = row[n + 1];
    for (int k = row[n]; k < k1; ++k) {
        int s = srcs[k];
        sum = fmaf(dinv[s], p[s * NCLS + c], sum);
    }
    out[t] = fmaf(dn, sum, b2[c]);
}

// ------------------- log_softmax over 10 classes, in place
__global__ __launch_bounds__(256) void k_lsm(float* __restrict__ out) {
    int n = blockIdx.x * 256 + threadIdx.x;
    if (n >= N_NODES) return;
    float v[NCLS];
    float m = -1e30f;
#pragma unroll
    for (int c = 0; c < NCLS; ++c) {
        v[c] = out[n * NCLS + c];
        m = fmaxf(m, v[c]);
    }
    float s = 0.f;
#pragma unroll
    for (int c = 0; c < NCLS; ++c) s += __expf(v[c] - m);
    float l = __logf(s) + m;
#pragma unroll
    for (int c = 0; c < NCLS; ++c) out[n * NCLS + c] = v[c] - l;
}

extern "C" void kernel_launch(void* const* d_in, const int* in_sizes, int n_in,
                              void* d_out, int out_size, void* d_ws, size_t ws_size,
                              hipStream_t stream) {
    const float* x  = (const float*)d_in[0];
    const int*   ei = (const int*)d_in[1];   // [2,E] int32: row0=src, row1=dst
    const float* W1 = (const float*)d_in[2];
    const float* b1 = (const float*)d_in[3];
    const float* W2 = (const float*)d_in[4];
    const float* b2 = (const float*)d_in[5];
    float* out = (float*)d_out;

    // workspace layout (4-byte units), total ~27.1 MB:
    // dinv[102400] | cnt/head[102400] | row[102400] | partials[512] |
    // srcs[3.2M] | h1/p[1.6384M] | agg1[1.6384M]
    float* f    = (float*)d_ws;
    float* dinv = f;
    int*   cnt  = (int*)(f + 102400);        // reused as `head` cursors after scan
    int*   row  = (int*)(f + 204800);        // N+1 entries
    int*   part = (int*)(f + 307200);
    int*   srcs = (int*)(f + 307712);
    float* h1   = f + 3507712;               // reused as `p` after layer 1
    float* agg1 = f + 5146112;
    float* p    = h1;

    k_zero <<<SCAN_BLOCKS, 256, 0, stream>>>(cnt);
    k_hist <<<(N_EDGES + 255) / 256, 256, 0, stream>>>(ei + N_EDGES, cnt);
    k_scan1<<<SCAN_BLOCKS, 256, 0, stream>>>(cnt, row, part, dinv);
    k_scan2<<<1, 512, 0, stream>>>(part);
    k_scan3<<<SCAN_BLOCKS, 256, 0, stream>>>(cnt, row, part, cnt /*head*/);
    k_place<<<(N_EDGES + 255) / 256, 256, 0, stream>>>(ei, cnt /*head*/, srcs);

    k_gemm1<<<2048, 256, 0, stream>>>(x, W1, h1);
    k_edge1g<<<(N_NODES * HID + 255) / 256, 256, 0, stream>>>(row, srcs, dinv, h1, b1, agg1);
    k_gemm2<<<(N_NODES * NCLS + 255) / 256, 256, 0, stream>>>(agg1, W2, p);
    k_edge2g<<<(N_NODES * NCLS + 255) / 256, 256, 0, stream>>>(row, srcs, dinv, p, b2, out);
    k_lsm  <<<(N_NODES + 255) / 256, 256, 0, stream>>>(out);
}

// Round 3
// 570.231 us; speedup vs baseline: 1.7204x; 1.6429x over previous
//
#include <hip/hip_runtime.h>

#define N_NODES 100000
#define N_EDGES 3200000
#define F_IN    512
#define HID     16
#define NCLS    10
#define NB      196        // ceil(100000/512) buckets of 512 nodes
#define EPB     4096       // edges per block in k_bpart

// ---------------- zero the padded bucket counters (re-poisoned every call)
__global__ __launch_bounds__(256) void k_binit(int* __restrict__ bcntp) {
    int i = blockIdx.x * 256 + threadIdx.x;
    if (i < NB * 16) bcntp[i] = 0;
}

// ---------------- bucket histogram via LDS (196 buckets, dst>>9)
__global__ __launch_bounds__(256) void k_bhist(const int* __restrict__ dst,
                                               int* __restrict__ bcntp) {
    __shared__ int h[256];
    int t = threadIdx.x;
    h[t] = 0;
    __syncthreads();
    int hi = min(N_EDGES, (int)(blockIdx.x + 1) * 8192);
    for (int e = blockIdx.x * 8192 + t; e < hi; e += 256)
        atomicAdd(&h[dst[e] >> 9], 1);
    __syncthreads();
    if (t < NB) {
        int v = h[t];
        if (v) atomicAdd(&bcntp[t * 16], v);   // padded: 1 counter per 64B line
    }
}

// ---------------- scan bucket counts -> boff[NB+1], init padded cursors
__global__ __launch_bounds__(256) void k_bscan(const int* __restrict__ bcntp,
                                               int* __restrict__ boff,
                                               int* __restrict__ bcurp,
                                               int* __restrict__ row) {
    __shared__ int sh[256];
    int t = threadIdx.x;
    int v = (t < NB) ? bcntp[t * 16] : 0;
    sh[t] = v;
    __syncthreads();
    for (int off = 1; off < 256; off <<= 1) {
        int add = (t >= off) ? sh[t - off] : 0;
        __syncthreads();
        sh[t] += add;
        __syncthreads();
    }
    int excl = sh[t] - v;
    if (t < NB) { boff[t] = excl; bcurp[t * 16] = excl; }
    if (t == 0) { boff[NB] = N_EDGES; row[N_NODES] = N_EDGES; }
}

// ---------------- multisplit partition: edges -> bucket-contiguous packed array
// packed word: ((d & 511) << 17) | s   (s < 2^17, local d < 2^9)
__global__ __launch_bounds__(256) void k_bpart(const int* __restrict__ ei,
                                               int* __restrict__ bcurp,
                                               int* __restrict__ part) {
    __shared__ int cnt_sh[256], base_sh[256];
    int t = threadIdx.x;
    cnt_sh[t] = 0;
    __syncthreads();
    int base = blockIdx.x * EPB;
    int pk[16], bk[16], rk[16];
#pragma unroll
    for (int j = 0; j < 16; ++j) {
        int e = base + j * 256 + t;
        if (e < N_EDGES) {
            int s = ei[e], d = ei[N_EDGES + e];
            bk[j] = d >> 9;
            pk[j] = ((d & 511) << 17) | s;
            rk[j] = atomicAdd(&cnt_sh[bk[j]], 1);
        } else bk[j] = -1;
    }
    __syncthreads();
    if (t < NB && cnt_sh[t] > 0)
        base_sh[t] = atomicAdd(&bcurp[t * 16], cnt_sh[t]);
    __syncthreads();
#pragma unroll
    for (int j = 0; j < 16; ++j)
        if (bk[j] >= 0) part[base_sh[bk[j]] + rk[j]] = pk[j];
}

// ---------------- per-bucket: node counts, scan, row/dinv, place srcs (all LDS)
__global__ __launch_bounds__(256) void k_bucket(const int* __restrict__ boff,
                                                const int* __restrict__ part,
                                                int* __restrict__ row,
                                                float* __restrict__ dinv,
                                                int* __restrict__ srcs) {
    __shared__ int cnt[512], ofs[512], sc[256];
    int t = threadIdx.x;
    int b = blockIdx.x;
    int e0 = boff[b], e1 = boff[b + 1];
    int nbase = b << 9;
    cnt[t] = 0; cnt[t + 256] = 0;
    __syncthreads();
    for (int e = e0 + t; e < e1; e += 256)
        atomicAdd(&cnt[part[e] >> 17], 1);
    __syncthreads();
    // exclusive scan of cnt[512] with 256 threads (2 elems/thread)
    int a0 = cnt[2 * t], a1 = cnt[2 * t + 1];
    sc[t] = a0 + a1;
    __syncthreads();
    for (int off = 1; off < 256; off <<= 1) {
        int add = (t >= off) ? sc[t - off] : 0;
        __syncthreads();
        sc[t] += add;
        __syncthreads();
    }
    int excl = sc[t] - (a0 + a1);
    ofs[2 * t] = excl;
    ofs[2 * t + 1] = excl + a0;
    __syncthreads();
    // emit row + dinv (coalesced), nodes [nbase, nbase+512) ∩ [0, N)
#pragma unroll
    for (int r = 0; r < 2; ++r) {
        int ln = t + r * 256;
        int n = nbase + ln;
        if (n < N_NODES) {
            row[n] = e0 + ofs[ln];
            dinv[n] = rsqrtf((float)(cnt[ln] + 1));   // +1 self-loop
        }
    }
    __syncthreads();
    // place: cursors live in ofs[]; writes confined to [e0,e1) (~64KB window)
    for (int e = e0 + t; e < e1; e += 256) {
        int pp = part[e];
        int pos = atomicAdd(&ofs[pp >> 17], 1);
        srcs[e0 + pos] = pp & 0x1FFFF;
    }
}

// ---------------- h1s = dinv[n] * (x @ W1)  (wave per node, W1 in VGPRs)
__global__ __launch_bounds__(256) void k_gemm1(const float* __restrict__ x,
                                               const float* __restrict__ W1,
                                               const float* __restrict__ dinv,
                                               float* __restrict__ h1s) {
    const int lane = threadIdx.x & 63;
    const int wid = (blockIdx.x * 256 + threadIdx.x) >> 6;
    const int nwaves = (gridDim.x * 256) >> 6;

    float w[8][16];
#pragma unroll
    for (int i = 0; i < 8; ++i) {
        const float* wr = W1 + (lane * 8 + i) * 16;
#pragma unroll
        for (int j = 0; j < 16; ++j) w[i][j] = wr[j];
    }

    for (int n = wid; n < N_NODES; n += nwaves) {
        const float4* xr = (const float4*)(x + (size_t)n * F_IN);
        float4 a = xr[lane * 2];
        float4 b = xr[lane * 2 + 1];
        float xv[8] = {a.x, a.y, a.z, a.w, b.x, b.y, b.z, b.w};
        float acc[16];
#pragma unroll
        for (int j = 0; j < 16; ++j) acc[j] = 0.f;
#pragma unroll
        for (int i = 0; i < 8; ++i)
#pragma unroll
            for (int j = 0; j < 16; ++j) acc[j] = fmaf(xv[i], w[i][j], acc[j]);
#pragma unroll
        for (int off = 32; off > 0; off >>= 1)
#pragma unroll
            for (int j = 0; j < 16; ++j) acc[j] += __shfl_xor(acc[j], off, 64);
        if (lane == 0) {
            float dn = dinv[n];
            float4* o = (float4*)(h1s + n * HID);
            o[0] = make_float4(acc[0] * dn, acc[1] * dn, acc[2] * dn, acc[3] * dn);
            o[1] = make_float4(acc[4] * dn, acc[5] * dn, acc[6] * dn, acc[7] * dn);
            o[2] = make_float4(acc[8] * dn, acc[9] * dn, acc[10] * dn, acc[11] * dn);
            o[3] = make_float4(acc[12] * dn, acc[13] * dn, acc[14] * dn, acc[15] * dn);
        }
    }
}

// ---------------- layer-1 aggregate (gather, 4-way unroll), fused +b1, relu
__global__ __launch_bounds__(256) void k_edge1g(const int* __restrict__ row,
                                                const int* __restrict__ srcs,
                                                const float* __restrict__ dinv,
                                                const float* __restrict__ h1s,
                                                const float* __restrict__ b1,
                                                float* __restrict__ agg1) {
    int t = blockIdx.x * 256 + threadIdx.x;
    if (t >= N_NODES * HID) return;
    int n = t >> 4, j = t & 15;
    float sum = h1s[t];                        // self-loop (pre-scaled by dinv[n])
    int k = row[n], k1 = row[n + 1];
    for (; k + 4 <= k1; k += 4) {
        int s0 = srcs[k], s1 = srcs[k + 1], s2 = srcs[k + 2], s3 = srcs[k + 3];
        float v0 = h1s[s0 * HID + j], v1 = h1s[s1 * HID + j];
        float v2 = h1s[s2 * HID + j], v3 = h1s[s3 * HID + j];
        sum += (v0 + v1) + (v2 + v3);
    }
    for (; k < k1; ++k) sum += h1s[srcs[k] * HID + j];
    agg1[t] = fmaxf(fmaf(dinv[n], sum, b1[j]), 0.f);
}

// ---------------- ps = dinv[n] * (agg1 @ W2)
__global__ __launch_bounds__(256) void k_gemm2(const float* __restrict__ agg1,
                                               const float* __restrict__ W2,
                                               const float* __restrict__ dinv,
                                               float* __restrict__ ps) {
    int t = blockIdx.x * 256 + threadIdx.x;
    if (t >= N_NODES * NCLS) return;
    int n = t / NCLS, c = t - n * NCLS;
    const float* r = agg1 + n * HID;
    float v = 0.f;
#pragma unroll
    for (int j = 0; j < HID; ++j) v = fmaf(r[j], W2[j * NCLS + c], v);
    ps[t] = v * dinv[n];
}

// ---------------- layer-2 aggregate (gather, 4-way unroll), fused +b2
__global__ __launch_bounds__(256) void k_edge2g(const int* __restrict__ row,
                                                const int* __restrict__ srcs,
                                                const float* __restrict__ dinv,
                                                const float* __restrict__ ps,
                                                const float* __restrict__ b2,
                                                float* __restrict__ out) {
    int t = blockIdx.x * 256 + threadIdx.x;
    if (t >= N_NODES * NCLS) return;
    int n = t / NCLS, c = t - n * NCLS;
    float sum = ps[t];                          // self-loop
    int k = row[n], k1 = row[n + 1];
    for (; k + 4 <= k1; k += 4) {
        int s0 = srcs[k], s1 = srcs[k + 1], s2 = srcs[k + 2], s3 = srcs[k + 3];
        float v0 = ps[s0 * NCLS + c], v1 = ps[s1 * NCLS + c];
        float v2 = ps[s2 * NCLS + c], v3 = ps[s3 * NCLS + c];
        sum += (v0 + v1) + (v2 + v3);
    }
    for (; k < k1; ++k) sum += ps[srcs[k] * NCLS + c];
    out[t] = fmaf(dinv[n], sum, b2[c]);
}

// ---------------- log_softmax over 10 classes, in place
__global__ __launch_bounds__(256) void k_lsm(float* __restrict__ out) {
    int n = blockIdx.x * 256 + threadIdx.x;
    if (n >= N_NODES) return;
    float v[NCLS];
    float m = -1e30f;
#pragma unroll
    for (int c = 0; c < NCLS; ++c) {
        v[c] = out[n * NCLS + c];
        m = fmaxf(m, v[c]);
    }
    float s = 0.f;
#pragma unroll
    for (int c = 0; c < NCLS; ++c) s += __expf(v[c] - m);
    float l = __logf(s) + m;
#pragma unroll
    for (int c = 0; c < NCLS; ++c) out[n * NCLS + c] = v[c] - l;
}

extern "C" void kernel_launch(void* const* d_in, const int* in_sizes, int n_in,
                              void* d_out, int out_size, void* d_ws, size_t ws_size,
                              hipStream_t stream) {
    const float* x  = (const float*)d_in[0];
    const int*   ei = (const int*)d_in[1];   // [2,E] int32: row0=src, row1=dst
    const float* W1 = (const float*)d_in[2];
    const float* b1 = (const float*)d_in[3];
    const float* W2 = (const float*)d_in[4];
    const float* b2 = (const float*)d_in[5];
    float* out = (float*)d_out;

    // workspace layout (4-byte units), ~39.6 MB total:
    int* w = (int*)d_ws;
    float* dinv = (float*)w;                 // 102400
    int*   row   = w + 102400;               // 102404 -> pad 102416
    int*   bcntp = w + 204816;               // 196*16 = 3136
    int*   bcurp = w + 207952;               // 3136
    int*   boff  = w + 211088;               // 197 -> pad 256
    int*   part  = w + 211344;               // 3.2M packed edges
    int*   srcs  = w + 3411344;              // 3.2M
    float* h1s   = (float*)(w + 6611344);    // 1.6384M (reused as ps)
    float* agg1  = (float*)(w + 8249744);    // 1.6384M
    float* ps    = h1s;

    // CSR build (bucketed, no scattered global atomics)
    k_binit<<<(NB * 16 + 255) / 256, 256, 0, stream>>>(bcntp);
    k_bhist<<<(N_EDGES + 8191) / 8192, 256, 0, stream>>>(ei + N_EDGES, bcntp);
    k_bscan<<<1, 256, 0, stream>>>(bcntp, boff, bcurp, row);
    k_bpart<<<(N_EDGES + EPB - 1) / EPB, 256, 0, stream>>>(ei, bcurp, part);
    k_bucket<<<NB, 256, 0, stream>>>(boff, part, row, dinv, srcs);

    // GCN layers
    k_gemm1 <<<2048, 256, 0, stream>>>(x, W1, dinv, h1s);
    k_edge1g<<<(N_NODES * HID + 255) / 256, 256, 0, stream>>>(row, srcs, dinv, h1s, b1, agg1);
    k_gemm2 <<<(N_NODES * NCLS + 255) / 256, 256, 0, stream>>>(agg1, W2, dinv, ps);
    k_edge2g<<<(N_NODES * NCLS + 255) / 256, 256, 0, stream>>>(row, srcs, dinv, ps, b2, out);
    k_lsm   <<<(N_NODES + 255) / 256, 256, 0, stream>>>(out);
}

// Round 4
// 531.000 us; speedup vs baseline: 1.8475x; 1.0739x over previous
//
#include <hip/hip_runtime.h>

#define N_NODES 100000
#define N_EDGES 3200000
#define F_IN    512
#define HID     16
#define NCLS    10
#define NB      196        // ceil(100000/512) buckets of 512 nodes
#define EPB     4096       // edges per block in k_bpart
#define TK      32         // gemm1 K-chunk

// ---------------- zero the padded bucket counters (re-poisoned every call)
__global__ __launch_bounds__(256) void k_binit(int* __restrict__ bcntp) {
    int i = blockIdx.x * 256 + threadIdx.x;
    if (i < NB * 16) bcntp[i] = 0;
}

// ---------------- bucket histogram via LDS (196 buckets, dst>>9)
__global__ __launch_bounds__(256) void k_bhist(const int* __restrict__ dst,
                                               int* __restrict__ bcntp) {
    __shared__ int h[256];
    int t = threadIdx.x;
    h[t] = 0;
    __syncthreads();
    int hi = min(N_EDGES, (int)(blockIdx.x + 1) * 8192);
    for (int e = blockIdx.x * 8192 + t; e < hi; e += 256)
        atomicAdd(&h[dst[e] >> 9], 1);
    __syncthreads();
    if (t < NB) {
        int v = h[t];
        if (v) atomicAdd(&bcntp[t * 16], v);   // padded: 1 counter per 64B line
    }
}

// ---------------- scan bucket counts -> boff[NB+1], init padded cursors
__global__ __launch_bounds__(256) void k_bscan(const int* __restrict__ bcntp,
                                               int* __restrict__ boff,
                                               int* __restrict__ bcurp,
                                               int* __restrict__ row) {
    __shared__ int sh[256];
    int t = threadIdx.x;
    int v = (t < NB) ? bcntp[t * 16] : 0;
    sh[t] = v;
    __syncthreads();
    for (int off = 1; off < 256; off <<= 1) {
        int add = (t >= off) ? sh[t - off] : 0;
        __syncthreads();
        sh[t] += add;
        __syncthreads();
    }
    int excl = sh[t] - v;
    if (t < NB) { boff[t] = excl; bcurp[t * 16] = excl; }
    if (t == 0) { boff[NB] = N_EDGES; row[N_NODES] = N_EDGES; }
}

// ---------------- multisplit partition: edges -> bucket-contiguous packed array
// packed word: ((d & 511) << 17) | s   (s < 2^17, local d < 2^9)
__global__ __launch_bounds__(256) void k_bpart(const int* __restrict__ ei,
                                               int* __restrict__ bcurp,
                                               int* __restrict__ part) {
    __shared__ int cnt_sh[256], base_sh[256];
    int t = threadIdx.x;
    cnt_sh[t] = 0;
    __syncthreads();
    int base = blockIdx.x * EPB;
    int pk[16], bk[16], rk[16];
#pragma unroll
    for (int j = 0; j < 16; ++j) {
        int e = base + j * 256 + t;
        if (e < N_EDGES) {
            int s = ei[e], d = ei[N_EDGES + e];
            bk[j] = d >> 9;
            pk[j] = ((d & 511) << 17) | s;
            rk[j] = atomicAdd(&cnt_sh[bk[j]], 1);
        } else bk[j] = -1;
    }
    __syncthreads();
    if (t < NB && cnt_sh[t] > 0)
        base_sh[t] = atomicAdd(&bcurp[t * 16], cnt_sh[t]);
    __syncthreads();
#pragma unroll
    for (int j = 0; j < 16; ++j)
        if (bk[j] >= 0) part[base_sh[bk[j]] + rk[j]] = pk[j];
}

// ---------------- per-bucket: node counts, scan, row/dinv, place srcs (all LDS)
__global__ __launch_bounds__(256) void k_bucket(const int* __restrict__ boff,
                                                const int* __restrict__ part,
                                                int* __restrict__ row,
                                                float* __restrict__ dinv,
                                                int* __restrict__ srcs) {
    __shared__ int cnt[512], ofs[512], sc[256];
    int t = threadIdx.x;
    int b = blockIdx.x;
    int e0 = boff[b], e1 = boff[b + 1];
    int nbase = b << 9;
    cnt[t] = 0; cnt[t + 256] = 0;
    __syncthreads();
    for (int e = e0 + t; e < e1; e += 256)
        atomicAdd(&cnt[part[e] >> 17], 1);
    __syncthreads();
    // exclusive scan of cnt[512] with 256 threads (2 elems/thread)
    int a0 = cnt[2 * t], a1 = cnt[2 * t + 1];
    sc[t] = a0 + a1;
    __syncthreads();
    for (int off = 1; off < 256; off <<= 1) {
        int add = (t >= off) ? sc[t - off] : 0;
        __syncthreads();
        sc[t] += add;
        __syncthreads();
    }
    int excl = sc[t] - (a0 + a1);
    ofs[2 * t] = excl;
    ofs[2 * t + 1] = excl + a0;
    __syncthreads();
#pragma unroll
    for (int r = 0; r < 2; ++r) {
        int ln = t + r * 256;
        int n = nbase + ln;
        if (n < N_NODES) {
            row[n] = e0 + ofs[ln];
            dinv[n] = rsqrtf((float)(cnt[ln] + 1));   // +1 self-loop
        }
    }
    __syncthreads();
    // place: cursors live in ofs[]; writes confined to [e0,e1) (~64KB window)
    for (int e = e0 + t; e < e1; e += 256) {
        int pp = part[e];
        int pos = atomicAdd(&ofs[pp >> 17], 1);
        srcs[e0 + pos] = pp & 0x1FFFF;
    }
}

// ---------------- h1s = dinv[n] * (x @ W1)
// thread-per-node; x staged in LDS (reg-prefetched one chunk ahead);
// W1 loads are wave-uniform -> expect s_load (SMEM pipe); 16 acc/thread.
__global__ __launch_bounds__(128) void k_gemm1(const float* __restrict__ x,
                                               const float* __restrict__ W1,
                                               const float* __restrict__ dinv,
                                               float* __restrict__ h1s) {
    __shared__ float xs[128][TK + 1];
    const int t = threadIdx.x;
    const int nbase = blockIdx.x * 128;
    const int f4 = t & 7;       // float4 index within chunk row (8 per row)
    const int r0 = t >> 3;      // 0..15; rows r0 + 16p

    float4 pre[8];
#pragma unroll
    for (int p = 0; p < 8; ++p) {
        int n = nbase + r0 + p * 16;
        pre[p] = (n < N_NODES) ? ((const float4*)(x + (size_t)n * F_IN))[f4]
                               : make_float4(0.f, 0.f, 0.f, 0.f);
    }

    float acc[16];
#pragma unroll
    for (int j = 0; j < 16; ++j) acc[j] = 0.f;

    for (int c = 0; c < F_IN; c += TK) {
        // commit prefetched chunk to LDS
#pragma unroll
        for (int p = 0; p < 8; ++p) {
            int r = r0 + p * 16;
            xs[r][f4 * 4 + 0] = pre[p].x;
            xs[r][f4 * 4 + 1] = pre[p].y;
            xs[r][f4 * 4 + 2] = pre[p].z;
            xs[r][f4 * 4 + 3] = pre[p].w;
        }
        __syncthreads();
        // prefetch next chunk (overlaps compute below)
        if (c + TK < F_IN) {
#pragma unroll
            for (int p = 0; p < 8; ++p) {
                int n = nbase + r0 + p * 16;
                pre[p] = (n < N_NODES)
                           ? ((const float4*)(x + (size_t)n * F_IN + c + TK))[f4]
                           : make_float4(0.f, 0.f, 0.f, 0.f);
            }
        }
        // compute: per k, 1 LDS read + 16 FMA with uniform W
#pragma unroll
        for (int k = 0; k < TK; ++k) {
            float xv = xs[t][k];
            const float4* wk = (const float4*)(W1 + (c + k) * 16);
            float4 wa = wk[0], wb = wk[1], wc = wk[2], wd = wk[3];
            acc[0]  = fmaf(xv, wa.x, acc[0]);
            acc[1]  = fmaf(xv, wa.y, acc[1]);
            acc[2]  = fmaf(xv, wa.z, acc[2]);
            acc[3]  = fmaf(xv, wa.w, acc[3]);
            acc[4]  = fmaf(xv, wb.x, acc[4]);
            acc[5]  = fmaf(xv, wb.y, acc[5]);
            acc[6]  = fmaf(xv, wb.z, acc[6]);
            acc[7]  = fmaf(xv, wb.w, acc[7]);
            acc[8]  = fmaf(xv, wc.x, acc[8]);
            acc[9]  = fmaf(xv, wc.y, acc[9]);
            acc[10] = fmaf(xv, wc.z, acc[10]);
            acc[11] = fmaf(xv, wc.w, acc[11]);
            acc[12] = fmaf(xv, wd.x, acc[12]);
            acc[13] = fmaf(xv, wd.y, acc[13]);
            acc[14] = fmaf(xv, wd.z, acc[14]);
            acc[15] = fmaf(xv, wd.w, acc[15]);
        }
        __syncthreads();
    }

    int n = nbase + t;
    if (n < N_NODES) {
        float dn = dinv[n];
        float4* o = (float4*)(h1s + (size_t)n * HID);
        o[0] = make_float4(acc[0] * dn,  acc[1] * dn,  acc[2] * dn,  acc[3] * dn);
        o[1] = make_float4(acc[4] * dn,  acc[5] * dn,  acc[6] * dn,  acc[7] * dn);
        o[2] = make_float4(acc[8] * dn,  acc[9] * dn,  acc[10] * dn, acc[11] * dn);
        o[3] = make_float4(acc[12] * dn, acc[13] * dn, acc[14] * dn, acc[15] * dn);
    }
}

// ---------------- layer-1 aggregate (gather, 4-way unroll), fused +b1, relu
__global__ __launch_bounds__(256) void k_edge1g(const int* __restrict__ row,
                                                const int* __restrict__ srcs,
                                                const float* __restrict__ dinv,
                                                const float* __restrict__ h1s,
                                                const float* __restrict__ b1,
                                                float* __restrict__ agg1) {
    int t = blockIdx.x * 256 + threadIdx.x;
    if (t >= N_NODES * HID) return;
    int n = t >> 4, j = t & 15;
    float sum = h1s[t];                        // self-loop (pre-scaled by dinv[n])
    int k = row[n], k1 = row[n + 1];
    for (; k + 4 <= k1; k += 4) {
        int s0 = srcs[k], s1 = srcs[k + 1], s2 = srcs[k + 2], s3 = srcs[k + 3];
        float v0 = h1s[s0 * HID + j], v1 = h1s[s1 * HID + j];
        float v2 = h1s[s2 * HID + j], v3 = h1s[s3 * HID + j];
        sum += (v0 + v1) + (v2 + v3);
    }
    for (; k < k1; ++k) sum += h1s[srcs[k] * HID + j];
    agg1[t] = fmaxf(fmaf(dinv[n], sum, b1[j]), 0.f);
}

// ---------------- ps = dinv[n] * (agg1 @ W2)
__global__ __launch_bounds__(256) void k_gemm2(const float* __restrict__ agg1,
                                               const float* __restrict__ W2,
                                               const float* __restrict__ dinv,
                                               float* __restrict__ ps) {
    int t = blockIdx.x * 256 + threadIdx.x;
    if (t >= N_NODES * NCLS) return;
    int n = t / NCLS, c = t - n * NCLS;
    const float* r = agg1 + n * HID;
    float v = 0.f;
#pragma unroll
    for (int j = 0; j < HID; ++j) v = fmaf(r[j], W2[j * NCLS + c], v);
    ps[t] = v * dinv[n];
}

// ---------------- layer-2 aggregate (gather, 4-way unroll), fused +b2
__global__ __launch_bounds__(256) void k_edge2g(const int* __restrict__ row,
                                                const int* __restrict__ srcs,
                                                const float* __restrict__ dinv,
                                                const float* __restrict__ ps,
                                                const float* __restrict__ b2,
                                                float* __restrict__ out) {
    int t = blockIdx.x * 256 + threadIdx.x;
    if (t >= N_NODES * NCLS) return;
    int n = t / NCLS, c = t - n * NCLS;
    float sum = ps[t];                          // self-loop
    int k = row[n], k1 = row[n + 1];
    for (; k + 4 <= k1; k += 4) {
        int s0 = srcs[k], s1 = srcs[k + 1], s2 = srcs[k + 2], s3 = srcs[k + 3];
        float v0 = ps[s0 * NCLS + c], v1 = ps[s1 * NCLS + c];
        float v2 = ps[s2 * NCLS + c], v3 = ps[s3 * NCLS + c];
        sum += (v0 + v1) + (v2 + v3);
    }
    for (; k < k1; ++k) sum += ps[srcs[k] * NCLS + c];
    out[t] = fmaf(dinv[n], sum, b2[c]);
}

// ---------------- log_softmax over 10 classes, in place
__global__ __launch_bounds__(256) void k_lsm(float* __restrict__ out) {
    int n = blockIdx.x * 256 + threadIdx.x;
    if (n >= N_NODES) return;
    float v[NCLS];
    float m = -1e30f;
#pragma unroll
    for (int c = 0; c < NCLS; ++c) {
        v[c] = out[n * NCLS + c];
        m = fmaxf(m, v[c]);
    }
    float s = 0.f;
#pragma unroll
    for (int c = 0; c < NCLS; ++c) s += __expf(v[c] - m);
    float l = __logf(s) + m;
#pragma unroll
    for (int c = 0; c < NCLS; ++c) out[n * NCLS + c] = v[c] - l;
}

extern "C" void kernel_launch(void* const* d_in, const int* in_sizes, int n_in,
                              void* d_out, int out_size, void* d_ws, size_t ws_size,
                              hipStream_t stream) {
    const float* x  = (const float*)d_in[0];
    const int*   ei = (const int*)d_in[1];   // [2,E] int32: row0=src, row1=dst
    const float* W1 = (const float*)d_in[2];
    const float* b1 = (const float*)d_in[3];
    const float* W2 = (const float*)d_in[4];
    const float* b2 = (const float*)d_in[5];
    float* out = (float*)d_out;

    int* w = (int*)d_ws;
    float* dinv = (float*)w;                 // 102400
    int*   row   = w + 102400;               // 102404 -> pad 102416
    int*   bcntp = w + 204816;               // 196*16 = 3136
    int*   bcurp = w + 207952;               // 3136
    int*   boff  = w + 211088;               // 197 -> pad 256
    int*   part  = w + 211344;               // 3.2M packed edges
    int*   srcs  = w + 3411344;              // 3.2M
    float* h1s   = (float*)(w + 6611344);    // 1.6384M (reused as ps)
    float* agg1  = (float*)(w + 8249744);    // 1.6384M
    float* ps    = h1s;

    // CSR build (bucketed, no scattered global atomics)
    k_binit<<<(NB * 16 + 255) / 256, 256, 0, stream>>>(bcntp);
    k_bhist<<<(N_EDGES + 8191) / 8192, 256, 0, stream>>>(ei + N_EDGES, bcntp);
    k_bscan<<<1, 256, 0, stream>>>(bcntp, boff, bcurp, row);
    k_bpart<<<(N_EDGES + EPB - 1) / EPB, 256, 0, stream>>>(ei, bcurp, part);
    k_bucket<<<NB, 256, 0, stream>>>(boff, part, row, dinv, srcs);

    // GCN layers
    k_gemm1 <<<(N_NODES + 127) / 128, 128, 0, stream>>>(x, W1, dinv, h1s);
    k_edge1g<<<(N_NODES * HID + 255) / 256, 256, 0, stream>>>(row, srcs, dinv, h1s, b1, agg1);
    k_gemm2 <<<(N_NODES * NCLS + 255) / 256, 256, 0, stream>>>(agg1, W2, dinv, ps);
    k_edge2g<<<(N_NODES * NCLS + 255) / 256, 256, 0, stream>>>(row, srcs, dinv, ps, b2, out);
    k_lsm   <<<(N_NODES + 255) / 256, 256, 0, stream>>>(out);
}

// Round 5
// 510.232 us; speedup vs baseline: 1.9227x; 1.0407x over previous
//
#include <hip/hip_runtime.h>

#define N_NODES 100000
#define N_EDGES 3200000
#define F_IN    512
#define HID     16
#define NCLS    10
#define NB      196        // ceil(100000/512) buckets of 512 nodes
#define EPB     4096       // edges per block in k_bpart
#define TK      32         // gemm1 K-chunk
#define PS      12         // padded ps row stride (>= NCLS, 16B-aligned rows)

// ---------------- zero the padded bucket counters (re-poisoned every call)
__global__ __launch_bounds__(256) void k_binit(int* __restrict__ bcntp) {
    int i = blockIdx.x * 256 + threadIdx.x;
    if (i < NB * 16) bcntp[i] = 0;
}

// ---------------- bucket histogram via LDS (196 buckets, dst>>9)
__global__ __launch_bounds__(256) void k_bhist(const int* __restrict__ dst,
                                               int* __restrict__ bcntp) {
    __shared__ int h[256];
    int t = threadIdx.x;
    h[t] = 0;
    __syncthreads();
    int hi = min(N_EDGES, (int)(blockIdx.x + 1) * 8192);
    for (int e = blockIdx.x * 8192 + t; e < hi; e += 256)
        atomicAdd(&h[dst[e] >> 9], 1);
    __syncthreads();
    if (t < NB) {
        int v = h[t];
        if (v) atomicAdd(&bcntp[t * 16], v);   // padded: 1 counter per 64B line
    }
}

// ---------------- scan bucket counts -> boff[NB+1], init padded cursors
__global__ __launch_bounds__(256) void k_bscan(const int* __restrict__ bcntp,
                                               int* __restrict__ boff,
                                               int* __restrict__ bcurp,
                                               int* __restrict__ row) {
    __shared__ int sh[256];
    int t = threadIdx.x;
    int v = (t < NB) ? bcntp[t * 16] : 0;
    sh[t] = v;
    __syncthreads();
    for (int off = 1; off < 256; off <<= 1) {
        int add = (t >= off) ? sh[t - off] : 0;
        __syncthreads();
        sh[t] += add;
        __syncthreads();
    }
    int excl = sh[t] - v;
    if (t < NB) { boff[t] = excl; bcurp[t * 16] = excl; }
    if (t == 0) { boff[NB] = N_EDGES; row[N_NODES] = N_EDGES; }
}

// ---------------- multisplit partition: edges -> bucket-contiguous packed array
// packed word: ((d & 511) << 17) | s   (s < 2^17, local d < 2^9)
__global__ __launch_bounds__(256) void k_bpart(const int* __restrict__ ei,
                                               int* __restrict__ bcurp,
                                               int* __restrict__ part) {
    __shared__ int cnt_sh[256], base_sh[256];
    int t = threadIdx.x;
    cnt_sh[t] = 0;
    __syncthreads();
    int base = blockIdx.x * EPB;
    int pk[16], bk[16], rk[16];
#pragma unroll
    for (int j = 0; j < 16; ++j) {
        int e = base + j * 256 + t;
        if (e < N_EDGES) {
            int s = ei[e], d = ei[N_EDGES + e];
            bk[j] = d >> 9;
            pk[j] = ((d & 511) << 17) | s;
            rk[j] = atomicAdd(&cnt_sh[bk[j]], 1);
        } else bk[j] = -1;
    }
    __syncthreads();
    if (t < NB && cnt_sh[t] > 0)
        base_sh[t] = atomicAdd(&bcurp[t * 16], cnt_sh[t]);
    __syncthreads();
#pragma unroll
    for (int j = 0; j < 16; ++j)
        if (bk[j] >= 0) part[base_sh[bk[j]] + rk[j]] = pk[j];
}

// ---------------- per-bucket: node counts, scan, row/dinv, place srcs (all LDS)
__global__ __launch_bounds__(256) void k_bucket(const int* __restrict__ boff,
                                                const int* __restrict__ part,
                                                int* __restrict__ row,
                                                float* __restrict__ dinv,
                                                int* __restrict__ srcs) {
    __shared__ int cnt[512], ofs[512], sc[256];
    int t = threadIdx.x;
    int b = blockIdx.x;
    int e0 = boff[b], e1 = boff[b + 1];
    int nbase = b << 9;
    cnt[t] = 0; cnt[t + 256] = 0;
    __syncthreads();
    for (int e = e0 + t; e < e1; e += 256)
        atomicAdd(&cnt[part[e] >> 17], 1);
    __syncthreads();
    int a0 = cnt[2 * t], a1 = cnt[2 * t + 1];
    sc[t] = a0 + a1;
    __syncthreads();
    for (int off = 1; off < 256; off <<= 1) {
        int add = (t >= off) ? sc[t - off] : 0;
        __syncthreads();
        sc[t] += add;
        __syncthreads();
    }
    int excl = sc[t] - (a0 + a1);
    ofs[2 * t] = excl;
    ofs[2 * t + 1] = excl + a0;
    __syncthreads();
#pragma unroll
    for (int r = 0; r < 2; ++r) {
        int ln = t + r * 256;
        int n = nbase + ln;
        if (n < N_NODES) {
            row[n] = e0 + ofs[ln];
            dinv[n] = rsqrtf((float)(cnt[ln] + 1));   // +1 self-loop
        }
    }
    __syncthreads();
    for (int e = e0 + t; e < e1; e += 256) {
        int pp = part[e];
        int pos = atomicAdd(&ofs[pp >> 17], 1);
        srcs[e0 + pos] = pp & 0x1FFFF;
    }
}

// ---------------- h1s = dinv[n] * (x @ W1)
// thread-per-node; x AND the 32x16 W-chunk staged in LDS (reg-prefetched one
// chunk ahead). Inner loop is pure LDS (homogeneous lgkmcnt, pipelines fine).
// LDS = 16.9KB + 2KB -> 8 blocks/CU, 16 waves/CU.
__global__ __launch_bounds__(128) void k_gemm1(const float* __restrict__ x,
                                               const float* __restrict__ W1,
                                               const float* __restrict__ dinv,
                                               float* __restrict__ h1s) {
    __shared__ float xs[128][TK + 1];
    __shared__ float wchunk[TK * 16];      // 512 floats = 128 float4
    const int t = threadIdx.x;
    const int nbase = blockIdx.x * 128;
    const int f4 = t & 7;       // float4 index within chunk row (8 per row)
    const int r0 = t >> 3;      // 0..15; rows r0 + 16p

    float4 pre[8];
#pragma unroll
    for (int p = 0; p < 8; ++p) {
        int n = nbase + r0 + p * 16;
        pre[p] = (n < N_NODES) ? ((const float4*)(x + (size_t)n * F_IN))[f4]
                               : make_float4(0.f, 0.f, 0.f, 0.f);
    }
    float4 wpre = ((const float4*)W1)[t];   // chunk 0's W rows (32x16 = 128 f4)

    float acc[16];
#pragma unroll
    for (int j = 0; j < 16; ++j) acc[j] = 0.f;

    for (int c = 0; c < F_IN; c += TK) {
        // commit prefetched x-chunk and W-chunk to LDS
#pragma unroll
        for (int p = 0; p < 8; ++p) {
            int r = r0 + p * 16;
            xs[r][f4 * 4 + 0] = pre[p].x;
            xs[r][f4 * 4 + 1] = pre[p].y;
            xs[r][f4 * 4 + 2] = pre[p].z;
            xs[r][f4 * 4 + 3] = pre[p].w;
        }
        ((float4*)wchunk)[t] = wpre;
        __syncthreads();
        // prefetch next chunk (overlaps compute below)
        if (c + TK < F_IN) {
#pragma unroll
            for (int p = 0; p < 8; ++p) {
                int n = nbase + r0 + p * 16;
                pre[p] = (n < N_NODES)
                           ? ((const float4*)(x + (size_t)n * F_IN + c + TK))[f4]
                           : make_float4(0.f, 0.f, 0.f, 0.f);
            }
            wpre = ((const float4*)(W1 + (c + TK) * 16))[t];
        }
        // compute: per k, 1 LDS b32 + 4 LDS b128 broadcast + 16 FMA
#pragma unroll
        for (int k = 0; k < TK; ++k) {
            float xv = xs[t][k];
            const float4* wk = (const float4*)&wchunk[k * 16];
            float4 wa = wk[0], wb = wk[1], wc = wk[2], wd = wk[3];
            acc[0]  = fmaf(xv, wa.x, acc[0]);
            acc[1]  = fmaf(xv, wa.y, acc[1]);
            acc[2]  = fmaf(xv, wa.z, acc[2]);
            acc[3]  = fmaf(xv, wa.w, acc[3]);
            acc[4]  = fmaf(xv, wb.x, acc[4]);
            acc[5]  = fmaf(xv, wb.y, acc[5]);
            acc[6]  = fmaf(xv, wb.z, acc[6]);
            acc[7]  = fmaf(xv, wb.w, acc[7]);
            acc[8]  = fmaf(xv, wc.x, acc[8]);
            acc[9]  = fmaf(xv, wc.y, acc[9]);
            acc[10] = fmaf(xv, wc.z, acc[10]);
            acc[11] = fmaf(xv, wc.w, acc[11]);
            acc[12] = fmaf(xv, wd.x, acc[12]);
            acc[13] = fmaf(xv, wd.y, acc[13]);
            acc[14] = fmaf(xv, wd.z, acc[14]);
            acc[15] = fmaf(xv, wd.w, acc[15]);
        }
        __syncthreads();
    }

    int n = nbase + t;
    if (n < N_NODES) {
        float dn = dinv[n];
        float4* o = (float4*)(h1s + (size_t)n * HID);
        o[0] = make_float4(acc[0] * dn,  acc[1] * dn,  acc[2] * dn,  acc[3] * dn);
        o[1] = make_float4(acc[4] * dn,  acc[5] * dn,  acc[6] * dn,  acc[7] * dn);
        o[2] = make_float4(acc[8] * dn,  acc[9] * dn,  acc[10] * dn, acc[11] * dn);
        o[3] = make_float4(acc[12] * dn, acc[13] * dn, acc[14] * dn, acc[15] * dn);
    }
}

// ---------------- layer-1 aggregate: quad-per-node, float4 gathers.
// One gather instr covers 16 edges x full 64B line (4x fewer TA transactions).
__global__ __launch_bounds__(256) void k_edge1g(const int* __restrict__ row,
                                                const int* __restrict__ srcs,
                                                const float* __restrict__ dinv,
                                                const float* __restrict__ h1s,
                                                const float* __restrict__ b1,
                                                float* __restrict__ agg1) {
    int t = blockIdx.x * 256 + threadIdx.x;
    if (t >= N_NODES * 4) return;
    int n = t >> 2, q = t & 3;
    const float4* h4 = (const float4*)h1s;
    float4 sum = h4[n * 4 + q];               // self-loop (pre-scaled by dinv[n])
    int k = row[n], k1 = row[n + 1];
    for (; k + 4 <= k1; k += 4) {
        int s0 = srcs[k], s1 = srcs[k + 1], s2 = srcs[k + 2], s3 = srcs[k + 3];
        float4 v0 = h4[s0 * 4 + q], v1 = h4[s1 * 4 + q];
        float4 v2 = h4[s2 * 4 + q], v3 = h4[s3 * 4 + q];
        sum.x += (v0.x + v1.x) + (v2.x + v3.x);
        sum.y += (v0.y + v1.y) + (v2.y + v3.y);
        sum.z += (v0.z + v1.z) + (v2.z + v3.z);
        sum.w += (v0.w + v1.w) + (v2.w + v3.w);
    }
    for (; k < k1; ++k) {
        float4 v = h4[srcs[k] * 4 + q];
        sum.x += v.x; sum.y += v.y; sum.z += v.z; sum.w += v.w;
    }
    float dn = dinv[n];
    float4 bb = ((const float4*)b1)[q];
    float4 r;
    r.x = fmaxf(fmaf(dn, sum.x, bb.x), 0.f);
    r.y = fmaxf(fmaf(dn, sum.y, bb.y), 0.f);
    r.z = fmaxf(fmaf(dn, sum.z, bb.z), 0.f);
    r.w = fmaxf(fmaf(dn, sum.w, bb.w), 0.f);
    ((float4*)agg1)[n * 4 + q] = r;
}

// ---------------- ps[n, 0..11] = dinv[n] * (agg1[n] @ W2), cols 10,11 = 0
__global__ __launch_bounds__(256) void k_gemm2(const float* __restrict__ agg1,
                                               const float* __restrict__ W2,
                                               const float* __restrict__ dinv,
                                               float* __restrict__ ps) {
    int t = blockIdx.x * 256 + threadIdx.x;
    if (t >= N_NODES * 3) return;
    int n = t / 3, c4 = t - n * 3;
    int c0 = c4 * 4;
    const float4* a4 = (const float4*)(agg1 + n * HID);
    float4 a0 = a4[0], a1 = a4[1], a2 = a4[2], a3 = a4[3];
    float aj[16] = {a0.x, a0.y, a0.z, a0.w, a1.x, a1.y, a1.z, a1.w,
                    a2.x, a2.y, a2.z, a2.w, a3.x, a3.y, a3.z, a3.w};
    float4 acc = make_float4(0.f, 0.f, 0.f, 0.f);
#pragma unroll
    for (int j = 0; j < HID; ++j) {
        float av = aj[j];
        acc.x = fmaf(av, W2[j * NCLS + c0], acc.x);
        acc.y = fmaf(av, W2[j * NCLS + c0 + 1], acc.y);
        acc.z = fmaf(av, (c0 + 2 < NCLS) ? W2[j * NCLS + c0 + 2] : 0.f, acc.z);
        acc.w = fmaf(av, (c0 + 3 < NCLS) ? W2[j * NCLS + c0 + 3] : 0.f, acc.w);
    }
    float dn = dinv[n];
    ((float4*)ps)[n * 3 + c4] =
        make_float4(acc.x * dn, acc.y * dn, acc.z * dn, acc.w * dn);
}

// ---------------- layer-2 aggregate + fused log_softmax.
// quad-per-node: q=0,1,2 cover cols 0..11 (10,11 zero); q=3 duplicates q=2's
// gather (kept convergent) but contributes 0 to the exp-sum.
__global__ __launch_bounds__(256) void k_edge2g(const int* __restrict__ row,
                                                const int* __restrict__ srcs,
                                                const float* __restrict__ dinv,
                                                const float* __restrict__ ps,
                                                const float* __restrict__ b2,
                                                float* __restrict__ out) {
    int t = blockIdx.x * 256 + threadIdx.x;
    if (t >= N_NODES * 4) return;
    int n = t >> 2, q = t & 3;
    int qc = (q < 3) ? q : 2;
    const float4* p4 = (const float4*)ps;
    float4 sum = p4[n * 3 + qc];              // self-loop
    int k = row[n], k1 = row[n + 1];
    for (; k + 4 <= k1; k += 4) {
        int s0 = srcs[k], s1 = srcs[k + 1], s2 = srcs[k + 2], s3 = srcs[k + 3];
        float4 v0 = p4[s0 * 3 + qc], v1 = p4[s1 * 3 + qc];
        float4 v2 = p4[s2 * 3 + qc], v3 = p4[s3 * 3 + qc];
        sum.x += (v0.x + v1.x) + (v2.x + v3.x);
        sum.y += (v0.y + v1.y) + (v2.y + v3.y);
        sum.z += (v0.z + v1.z) + (v2.z + v3.z);
        sum.w += (v0.w + v1.w) + (v2.w + v3.w);
    }
    for (; k < k1; ++k) {
        float4 v = p4[srcs[k] * 3 + qc];
        sum.x += v.x; sum.y += v.y; sum.z += v.z; sum.w += v.w;
    }
    float dn = dinv[n];
    int c0 = qc * 4;
    float4 val;
    val.x = fmaf(dn, sum.x, b2[c0]);
    val.y = fmaf(dn, sum.y, b2[c0 + 1]);
    val.z = (c0 + 2 < NCLS) ? fmaf(dn, sum.z, b2[c0 + 2]) : -1e30f;
    val.w = (c0 + 3 < NCLS) ? fmaf(dn, sum.w, b2[c0 + 3]) : -1e30f;
    // quad max (q=3 duplicates q=2 -> harmless for max)
    float m = fmaxf(fmaxf(val.x, val.y), fmaxf(val.z, val.w));
    m = fmaxf(m, __shfl_xor(m, 1));
    m = fmaxf(m, __shfl_xor(m, 2));
    // quad exp-sum (q=3 contributes 0)
    float se = __expf(val.x - m) + __expf(val.y - m)
             + __expf(val.z - m) + __expf(val.w - m);
    if (q == 3) se = 0.f;
    se += __shfl_xor(se, 1);
    se += __shfl_xor(se, 2);
    float l = m + __logf(se);
    // write out (stride 10): q0 -> c0..3, q1 -> c4..7, q2 -> c8..9
    if (q < 2) {
        float* o = out + n * NCLS + c0;
        o[0] = val.x - l; o[1] = val.y - l; o[2] = val.z - l; o[3] = val.w - l;
    } else if (q == 2) {
        float* o = out + n * NCLS + 8;
        o[0] = val.x - l; o[1] = val.y - l;
    }
}

extern "C" void kernel_launch(void* const* d_in, const int* in_sizes, int n_in,
                              void* d_out, int out_size, void* d_ws, size_t ws_size,
                              hipStream_t stream) {
    const float* x  = (const float*)d_in[0];
    const int*   ei = (const int*)d_in[1];   // [2,E] int32: row0=src, row1=dst
    const float* W1 = (const float*)d_in[2];
    const float* b1 = (const float*)d_in[3];
    const float* W2 = (const float*)d_in[4];
    const float* b2 = (const float*)d_in[5];
    float* out = (float*)d_out;

    int* w = (int*)d_ws;
    float* dinv = (float*)w;                 // 102400
    int*   row   = w + 102400;               // 102404 -> pad 102416
    int*   bcntp = w + 204816;               // 3136
    int*   bcurp = w + 207952;               // 3136
    int*   boff  = w + 211088;               // 197 -> pad 256
    int*   part  = w + 211344;               // 3.2M packed edges
    int*   srcs  = w + 3411344;              // 3.2M
    float* h1s   = (float*)(w + 6611344);    // 1.6384M
    float* agg1  = (float*)(w + 8249744);    // 1.6384M
    float* ps    = (float*)(w + 9888144);    // 1.2M (stride-12 rows)

    // CSR build (bucketed, no scattered global atomics)
    k_binit<<<(NB * 16 + 255) / 256, 256, 0, stream>>>(bcntp);
    k_bhist<<<(N_EDGES + 8191) / 8192, 256, 0, stream>>>(ei + N_EDGES, bcntp);
    k_bscan<<<1, 256, 0, stream>>>(bcntp, boff, bcurp, row);
    k_bpart<<<(N_EDGES + EPB - 1) / EPB, 256, 0, stream>>>(ei, bcurp, part);
    k_bucket<<<NB, 256, 0, stream>>>(boff, part, row, dinv, srcs);

    // GCN layers
    k_gemm1 <<<(N_NODES + 127) / 128, 128, 0, stream>>>(x, W1, dinv, h1s);
    k_edge1g<<<(N_NODES * 4 + 255) / 256, 256, 0, stream>>>(row, srcs, dinv, h1s, b1, agg1);
    k_gemm2 <<<(N_NODES * 3 + 255) / 256, 256, 0, stream>>>(agg1, W2, dinv, ps);
    k_edge2g<<<(N_NODES * 4 + 255) / 256, 256, 0, stream>>>(row, srcs, dinv, ps, b2, out);
}